// Round 6
// baseline (3190.237 us; speedup 1.0000x reference)
//
#include <hip/hip_runtime.h>
#include <stdint.h>

#define NCLS 80
#define NKER 256
#define STOT 3872
#define NFLAT (STOT*NCLS)   // 309760
#define NPRE 500
#define NPREP 512
#define MAXI 100
#define MH 160
#define MW 240
#define MP (MH*MW)          // 38400
#define OH 640
#define OW 960
#define NWORD 600           // 38400/64
#define PARTW 300           // 38400/128

// GEMM tiling
#define BN 128
#define BP 128
#define BK 16

// ---- workspace byte offsets ----
#define WS_HIST   0u          // 65536 u32 = 262144
#define WS_META   262144u
#define WS_IOU    266240u     // 500*500 f64 = 2,000,000
#define WS_ZEROB  2266240u    // memset range [0, WS_ZEROB): hist + meta + iou
#define WS_FLAT   2266240u    // 309760 f32 (dead after k_compact; reused as plist)
#define WS_CANDV  3505280u    // 4096 f32
#define WS_CANDI  3521664u    // 4096 i32
#define WS_SEL    3538048u    // 13 arrays x 4096B
#define WS_KPT    3591296u    // 256*512 f32 = 524,288
#define WS_MB     4115584u    // 500*600 u64 = 2,400,000
#define WS_PART   6515584u    // 500*300 f64 = 1,200,000
#define WS_SEG    7715584u    // 500*38400 u16 (bf16) -> ends ~46.1MB
#define WS_PLIST  WS_FLAT     // 124750 u32 max = 499KB < flat region

__device__ __forceinline__ float bf2f(unsigned short u) { return __uint_as_float(((unsigned)u) << 16); }
__device__ __forceinline__ unsigned short f2bf(float f) {
  unsigned b = __float_as_uint(f);
  return (unsigned short)((b + 0x7fffu + ((b >> 16) & 1u)) >> 16);
}
// monotone float->uint key (total order matching <)
__device__ __forceinline__ unsigned fkey(float f) {
  unsigned b = __float_as_uint(f);
  return b ^ ((b & 0x80000000u) ? 0xFFFFFFFFu : 0x80000000u);
}

// ---------- K1: point-NMS + threshold in LOGIT space (exact-equivalent, no exp) ----------
__global__ __launch_bounds__(256) void k_flat(
    const float* __restrict__ c0, const float* __restrict__ c1, const float* __restrict__ c2,
    const float* __restrict__ c3, const float* __restrict__ c4,
    float* __restrict__ flat, unsigned* __restrict__ hist) {
  int idx = blockIdx.x * 256 + threadIdx.x;
  if (idx >= NFLAT) return;
  int s = idx / NCLS, c = idx - s * NCLS;
  const float* base; int g, cell;
  if (s < 1600)      { base = c0; g = 40; cell = s; }
  else if (s < 2896) { base = c1; g = 36; cell = s - 1600; }
  else if (s < 3472) { base = c2; g = 24; cell = s - 2896; }
  else if (s < 3728) { base = c3; g = 16; cell = s - 3472; }
  else               { base = c4; g = 12; cell = s - 3728; }
  int i = cell / g, j = cell - i * g;
  const float* ch = base + c * g * g;
  float x = ch[i * g + j];
  float m = x;
  if (i > 0 && j > 0) m = fmaxf(m, ch[(i - 1) * g + j - 1]);
  if (i > 0)          m = fmaxf(m, ch[(i - 1) * g + j]);
  if (j > 0)          m = fmaxf(m, ch[i * g + j - 1]);
  bool pass = (x >= m) && ((double)x > -2.1972245773362196 /* ln(1/9) */);
  flat[idx] = pass ? x : __int_as_float(0xFF800000);  // -inf sentinel
  if (pass) atomicAdd(&hist[fkey(x) >> 16], 1u);
}

// ---------- K2: pivot bucket so that count(>= pivot) >= 500 ----------
__global__ void k_pivot(const unsigned* __restrict__ hist, unsigned* __restrict__ meta) {
  __shared__ unsigned csum[1024];
  int t = threadIdx.x;
  int hi = 65536 - t * 64, lo = hi - 64;
  unsigned s = 0;
  for (int b = lo; b < hi; ++b) s += hist[b];
  csum[t] = s;
  __syncthreads();
  if (t == 0) {
    unsigned cum = 0;
    for (int cch = 0; cch < 1024; ++cch) {
      if (cum + csum[cch] >= NPRE) {
        int chi = 65536 - cch * 64;
        for (int b = chi - 1; b >= chi - 64; --b) {
          if (cum + hist[b] >= NPRE) { meta[1] = (unsigned)b; return; }
          cum += hist[b];
        }
      }
      cum += csum[cch];
    }
    meta[1] = 0u;
  }
}

// ---------- K3: compact candidates (fp32 logit, index) ----------
__global__ __launch_bounds__(256) void k_compact(
    const float* __restrict__ flat, float* __restrict__ cv, int* __restrict__ ci,
    unsigned* __restrict__ meta) {
  int idx = blockIdx.x * 256 + threadIdx.x;
  if (idx >= NFLAT) return;
  float v = flat[idx];
  if (__float_as_uint(v) == 0xFF800000u) return;
  if ((fkey(v) >> 16) >= meta[1]) {
    unsigned pos = atomicAdd(&meta[0], 1u);
    if (pos < 4096u) { cv[pos] = v; ci[pos] = idx; }
  }
}

// ---------- K4: exact (logit,idx) bitonic sort, take top-500; fp64 sigmoid for winners ----------
__global__ __launch_bounds__(1024) void k_select(
    const float* __restrict__ cv, const int* __restrict__ ci, const unsigned* __restrict__ meta,
    double* __restrict__ sel_score, unsigned* __restrict__ sel_grid,
    unsigned* __restrict__ sel_label, double* __restrict__ sel_stride) {
  __shared__ float sv[4096];
  __shared__ int si[4096];
  int t = threadIdx.x;
  int n = (meta[0] < 4096u) ? (int)meta[0] : 4096;
  for (int i = t; i < 4096; i += 1024) {
    if (i < n) { sv[i] = cv[i]; si[i] = ci[i]; }
    else       { sv[i] = __int_as_float(0xFF800000); si[i] = (1 << 30) + i; }
  }
  __syncthreads();
  for (int k = 2; k <= 4096; k <<= 1)
    for (int j = k >> 1; j > 0; j >>= 1) {
      for (int i = t; i < 4096; i += 1024) {
        int ix = i ^ j;
        if (ix > i) {
          float v1 = sv[i], v2 = sv[ix]; int i1 = si[i], i2 = si[ix];
          bool b2 = (v2 > v1) || (v2 == v1 && i2 < i1);
          bool dir = (i & k) == 0;
          if (dir == b2) { sv[i] = v2; sv[ix] = v1; si[i] = i2; si[ix] = i1; }
        }
      }
      __syncthreads();
    }
  for (int i = t; i < NPREP; i += 1024) {
    if (i < NPRE && i < n) {
      int fidx = si[i];
      unsigned gi = (unsigned)fidx / NCLS;
      sel_score[i] = 1.0 / (1.0 + exp(-(double)sv[i]));
      sel_grid[i] = gi;
      sel_label[i] = (unsigned)fidx - gi * NCLS;
      sel_stride[i] = gi < 2896u ? 8.0 : (gi < 3472u ? 16.0 : 32.0);
    } else {
      sel_score[i] = 0.0; sel_grid[i] = 0u; sel_label[i] = 0u; sel_stride[i] = 1e18;
    }
  }
}

// ---------- K5: gather kernel vectors transposed kpT[k][n] ----------
__global__ __launch_bounds__(256) void k_gather(
    const float* __restrict__ k0, const float* __restrict__ k1, const float* __restrict__ k2,
    const float* __restrict__ k3, const float* __restrict__ k4,
    const unsigned* __restrict__ sel_grid, float* __restrict__ kpT) {
  int tid = blockIdx.x * 256 + threadIdx.x;
  if (tid >= NPREP * NKER) return;
  int n = tid & (NPREP - 1);
  int k = tid >> 9;
  float v = 0.f;
  if (n < NPRE) {
    unsigned gi = sel_grid[n];
    const float* base; unsigned g, cell;
    if (gi < 1600u)      { base = k0; g = 40; cell = gi; }
    else if (gi < 2896u) { base = k1; g = 36; cell = gi - 1600u; }
    else if (gi < 3472u) { base = k2; g = 24; cell = gi - 2896u; }
    else if (gi < 3728u) { base = k3; g = 16; cell = gi - 3472u; }
    else                 { base = k4; g = 12; cell = gi - 3728u; }
    v = base[(unsigned)k * g * g + cell];
  }
  kpT[k * NPREP + n] = v;
}

// ---------- K6: fp64 GEMM, 128x128 tile, BK=16, register-prefetch double-buffer ----------
// fma chain per output is ascending k over identical f64 values -> bit-identical to prior rounds.
__global__ __launch_bounds__(256, 4) void k_gemm(
    const float* __restrict__ kpT, const float* __restrict__ mf,
    unsigned short* __restrict__ seg, unsigned long long* __restrict__ mb,
    double* __restrict__ part) {
  __shared__ double Asd[BK][BN];   // 16KB [k][n]
  __shared__ double Bsd[BK][BP];   // 16KB [k][p]
  int p0 = blockIdx.x * BP, n0 = blockIdx.y * BN;
  int tid = threadIdx.x;
  int tp = tid & 15, tn = tid >> 4;
  double acc[8][8] = {};
  float2 ra[4], rb[4];
  // prologue: load tile 0 to regs
#pragma unroll
  for (int it = 0; it < 4; ++it) {
    int q = it * 256 + tid; int row = q >> 6, c2 = q & 63;
    ra[it] = *(const float2*)&kpT[row * NPREP + n0 + c2 * 2];
    rb[it] = *(const float2*)&mf[(size_t)row * MP + p0 + c2 * 2];
  }
  for (int kc = 0; kc < NKER; kc += BK) {
    // regs -> LDS (convert to f64)
#pragma unroll
    for (int it = 0; it < 4; ++it) {
      int q = it * 256 + tid; int row = q >> 6, c2 = q & 63;
      double2 da; da.x = (double)ra[it].x; da.y = (double)ra[it].y;
      double2 db; db.x = (double)rb[it].x; db.y = (double)rb[it].y;
      *(double2*)&Asd[row][c2 * 2] = da;
      *(double2*)&Bsd[row][c2 * 2] = db;
    }
    __syncthreads();
    // prefetch next tile while computing this one
    if (kc + BK < NKER) {
#pragma unroll
      for (int it = 0; it < 4; ++it) {
        int q = it * 256 + tid; int row = q >> 6, c2 = q & 63;
        ra[it] = *(const float2*)&kpT[(kc + BK + row) * NPREP + n0 + c2 * 2];
        rb[it] = *(const float2*)&mf[(size_t)(kc + BK + row) * MP + p0 + c2 * 2];
      }
    }
#pragma unroll 4
    for (int k = 0; k < BK; ++k) {
      double2 A0 = *(double2*)&Asd[k][tn * 8 + 0];
      double2 A1 = *(double2*)&Asd[k][tn * 8 + 2];
      double2 A2 = *(double2*)&Asd[k][tn * 8 + 4];
      double2 A3 = *(double2*)&Asd[k][tn * 8 + 6];
      double2 B0 = *(double2*)&Bsd[k][tp * 2];
      double2 B1 = *(double2*)&Bsd[k][32 + tp * 2];
      double2 B2 = *(double2*)&Bsd[k][64 + tp * 2];
      double2 B3 = *(double2*)&Bsd[k][96 + tp * 2];
      double a[8] = {A0.x, A0.y, A1.x, A1.y, A2.x, A2.y, A3.x, A3.y};
      double b[8] = {B0.x, B0.y, B1.x, B1.y, B2.x, B2.y, B3.x, B3.y};
#pragma unroll
      for (int r = 0; r < 8; ++r)
#pragma unroll
        for (int c = 0; c < 8; ++c)
          acc[r][c] = fma(a[r], b[c], acc[r][c]);
    }
    __syncthreads();
  }
  // epilogue: bit = (z>0) exact; seg/wsum via fp32 sigmoid, fp64 accum
  double* partL = (double*)&Asd[0][0];            // [128][16] f64 = 16KB (fills Asd)
  unsigned* nibL = (unsigned*)&Bsd[0][0];         // [128][16] u32 = 8KB (in Bsd)
  for (int r = 0; r < 8; ++r) {
    int nl = (tn << 3) + r;
    int nn = n0 + nl;
    unsigned nb = 0; double wsum = 0.0;
    unsigned short u[8];
#pragma unroll
    for (int c = 0; c < 8; ++c) {
      float z = (float)acc[r][c];
      float sf = 1.0f / (1.0f + __expf(-z));
      u[c] = f2bf(sf);
      if (acc[r][c] > 0.0) { nb |= 1u << c; wsum += (double)sf; }
    }
    if (nn < NPRE) {
#pragma unroll
      for (int g = 0; g < 4; ++g) {
        ushort2 o; o.x = u[2 * g]; o.y = u[2 * g + 1];
        *(ushort2*)&seg[(size_t)nn * MP + p0 + g * 32 + tp * 2] = o;
      }
    }
    partL[nl * 16 + tp] = wsum;
    nibL[nl * 16 + tp] = nb;
  }
  __syncthreads();
  if (tid < 128) {
    int nn = n0 + tid;
    if (nn < NPRE) {
      double ssum = 0.0; unsigned long long w0 = 0ull, w1 = 0ull;
#pragma unroll
      for (int c = 0; c < 16; ++c) {
        ssum += partL[tid * 16 + c];
        unsigned long long nb = (unsigned long long)nibL[tid * 16 + c];
        w0 |= ((nb      & 3ull) << (c * 2)) | (((nb >> 2) & 3ull) << (32 + c * 2));
        w1 |= (((nb >> 4) & 3ull) << (c * 2)) | (((nb >> 6) & 3ull) << (32 + c * 2));
      }
      int bx = blockIdx.x;
      part[nn * PARTW + bx] = ssum;
      mb[nn * NWORD + bx * 2] = w0;
      mb[nn * NWORD + bx * 2 + 1] = w1;
    }
  }
}

// ---------- K7: per-instance reduce -> updated score ----------
__global__ void k_masks(const unsigned long long* __restrict__ mb, const double* __restrict__ part,
                        const double* __restrict__ sel_score, const double* __restrict__ sel_stride,
                        double* __restrict__ summask, double* __restrict__ upd) {
  int n = blockIdx.x, t = threadIdx.x;
  int cnt = 0; double ws = 0.0;
  for (int j = t; j < NWORD; j += 64) cnt += __popcll(mb[n * NWORD + j]);
  for (int j = t; j < PARTW; j += 64) ws += part[n * PARTW + j];
  for (int o = 32; o > 0; o >>= 1) { cnt += __shfl_down(cnt, o); ws += __shfl_down(ws, o); }
  if (t == 0) {
    double cf = (double)cnt;
    double ss = ws / fmax(cf, 1.0);
    double raw = sel_score[n];
    bool keep = (cf > sel_stride[n]) && (raw > 0.0);
    summask[n] = cf;
    upd[n] = keep ? raw * ss : 0.0;
  }
}

// ---------- K8: stable descending fp64 sort + same-label-alive pair list ----------
__global__ __launch_bounds__(512) void k_sort(
    const double* __restrict__ upd, const unsigned* __restrict__ sel_label, const double* __restrict__ summask,
    double* __restrict__ s_score, unsigned* __restrict__ s_slot, unsigned* __restrict__ s_label2,
    double* __restrict__ s_sum, unsigned* __restrict__ plist, unsigned* __restrict__ meta) {
  __shared__ double sv[NPREP];
  __shared__ int si[NPREP];
  __shared__ unsigned labv[NPREP];
  int t = threadIdx.x;
  sv[t] = (t < NPRE) ? upd[t] : -1.0;
  si[t] = t;
  __syncthreads();
  for (int k = 2; k <= NPREP; k <<= 1)
    for (int j = k >> 1; j > 0; j >>= 1) {
      int ix = t ^ j;
      if (ix > t) {
        double v1 = sv[t], v2 = sv[ix]; int i1 = si[t], i2 = si[ix];
        bool b2 = (v2 > v1) || (v2 == v1 && i2 < i1);
        bool dir = (t & k) == 0;
        if (dir == b2) { sv[t] = v2; sv[ix] = v1; si[t] = i2; si[ix] = i1; }
      }
      __syncthreads();
    }
  double sc = sv[t]; int slot = si[t];
  bool alive = sc > 0.0;
  unsigned lab = sel_label[slot];
  s_score[t] = alive ? sc : 0.0;
  s_slot[t] = (unsigned)slot;
  s_label2[t] = lab;
  s_sum[t] = (alive && slot < NPRE) ? summask[slot] : 0.0;
  labv[t] = alive ? lab : (0x10000u + (unsigned)t);  // unique sentinel for dead
  __syncthreads();
  // pair enumeration: thread t = row i
  if (t < NPRE) {
    unsigned li = labv[t];
    if (li < 0x10000u) {
      for (int j = t + 1; j < NPRE; ++j) {
        if (labv[j] == li) {
          unsigned pos = atomicAdd(&meta[2], 1u);
          plist[pos] = ((unsigned)t << 16) | (unsigned)j;
        }
      }
    }
  }
}

// ---------- K9: pairwise IoU via popcount over pair list ----------
__global__ __launch_bounds__(256) void k_inter(
    const unsigned long long* __restrict__ mb, const unsigned* __restrict__ s_slot,
    const double* __restrict__ s_sum, const unsigned* __restrict__ plist,
    const unsigned* __restrict__ meta, double* __restrict__ iou) {
  int wid = (blockIdx.x * 256 + threadIdx.x) >> 6;   // 0..255
  int lane = threadIdx.x & 63;
  unsigned npair = meta[2];
  for (unsigned pp = wid; pp < npair; pp += 256) {
    unsigned pk = plist[pp];
    int i = (int)(pk >> 16), j = (int)(pk & 0xFFFFu);
    const unsigned long long* A = mb + (size_t)s_slot[i] * NWORD;
    const unsigned long long* B = mb + (size_t)s_slot[j] * NWORD;
    int c = 0;
    for (int wd = lane; wd < NWORD; wd += 64) c += __popcll(A[wd] & B[wd]);
    for (int o = 32; o > 0; o >>= 1) c += __shfl_down(c, o);
    if (lane == 0) {
      double inter = (double)c;
      double uni = s_sum[i] + s_sum[j] - inter;
      iou[i * NPRE + j] = (uni > 0.0) ? inter / fmax(uni, 1.0) : 0.0;
    }
  }
}

// ---------- K10: fused matrix-NMS (LDS-tiled) + 0.05 threshold + stable top-100 ----------
#define TROWS 8
__global__ __launch_bounds__(512) void k_nms_top(
    const double* __restrict__ iou, const double* __restrict__ s_score,
    const unsigned* __restrict__ s_label2, const unsigned* __restrict__ s_slot,
    float* __restrict__ d_out, int maskN, unsigned* __restrict__ up_slot) {
  __shared__ double tile[TROWS][NPREP];   // 32KB
  __shared__ double compS[NPREP];          // 4KB
  __shared__ double sv[NPREP];
  __shared__ int si[NPREP];
  int t = threadIdx.x;
  // pass 1: compS[t] = max_{i<t} iou[i][t]
  double cm = 0.0;
  for (int i0 = 0; i0 < NPRE; i0 += TROWS) {
#pragma unroll
    for (int q = 0; q < TROWS; ++q) {
      int r = q, c = t;
      if (c < NPRE && (i0 + r) < NPRE) tile[r][c] = iou[(i0 + r) * NPRE + c];
    }
    __syncthreads();
    if (t < NPRE) {
#pragma unroll
      for (int r = 0; r < TROWS; ++r) {
        int i = i0 + r;
        if (i < t) cm = fmax(cm, tile[r][t]);
      }
    }
    __syncthreads();
  }
  compS[t] = cm;
  __syncthreads();
  // pass 2: m = max_{i<t} (iou^2 - compS[i]^2)
  double m = 0.0;
  for (int i0 = 0; i0 < NPRE; i0 += TROWS) {
#pragma unroll
    for (int q = 0; q < TROWS; ++q) {
      int r = q, c = t;
      if (c < NPRE && (i0 + r) < NPRE) tile[r][c] = iou[(i0 + r) * NPRE + c];
    }
    __syncthreads();
    if (t < NPRE) {
#pragma unroll
      for (int r = 0; r < TROWS; ++r) {
        int i = i0 + r;
        if (i < t) { double d = tile[r][t]; m = fmax(m, d * d - compS[i] * compS[i]); }
      }
    }
    __syncthreads();
  }
  double f = 0.0;
  if (t < NPRE) {
    f = s_score[t] * exp(-2.0 * m);
    if (f < 0.05) f = 0.0;
  }
  sv[t] = f; si[t] = t;
  __syncthreads();
  for (int k = 2; k <= NPREP; k <<= 1)
    for (int j = k >> 1; j > 0; j >>= 1) {
      int ix = t ^ j;
      if (ix > t) {
        double v1 = sv[t], v2 = sv[ix]; int i1 = si[t], i2 = si[ix];
        bool b2 = (v2 > v1) || (v2 == v1 && i2 < i1);
        bool dir = (t & k) == 0;
        if (dir == b2) { sv[t] = v2; sv[ix] = v1; si[t] = i2; si[ix] = i1; }
      }
      __syncthreads();
    }
  if (t < MAXI) {
    int pos = si[t];
    d_out[maskN + t] = (float)sv[t];
    d_out[maskN + MAXI + t] = (float)s_label2[pos];
    up_slot[t] = s_slot[pos];
  }
}

// ---------- K11: 4x bilinear upsample, 4 px/thread, float4 stores ----------
__global__ __launch_bounds__(256) void k_up(const unsigned short* __restrict__ seg,
                                            const unsigned* __restrict__ up_slot,
                                            float* __restrict__ out, int maskN) {
  int o4 = (blockIdx.x * 256 + threadIdx.x) * 4;
  if (o4 >= maskN) return;
  int m = o4 / (OH * OW);
  int rem = o4 - m * (OH * OW);
  int y = rem / OW;
  int x = rem - y * OW;
  int a = x >> 2;
  const unsigned short* row = seg + (size_t)up_slot[m] * MP;
  float sy = y * 0.25f - 0.375f;
  int y0 = (int)floorf(sy);
  float wy = sy - y0;
  int y0c = max(y0, 0), y1c = min(y0 + 1, MH - 1);
  const unsigned short* r0 = row + y0c * MW;
  const unsigned short* r1 = row + y1c * MW;
  int t0 = max(a - 1, 0), t1 = a, t2 = min(a + 1, MW - 1);
  float T0 = bf2f(r0[t0]), T1 = bf2f(r0[t1]), T2 = bf2f(r0[t2]);
  float B0 = bf2f(r1[t0]), B1 = bf2f(r1[t1]), B2 = bf2f(r1[t2]);
  float iwy = 1.f - wy;
  float4 o;
  o.x = iwy * (0.375f * T0 + 0.625f * T1) + wy * (0.375f * B0 + 0.625f * B1);
  o.y = iwy * (0.125f * T0 + 0.875f * T1) + wy * (0.125f * B0 + 0.875f * B1);
  o.z = iwy * (0.875f * T1 + 0.125f * T2) + wy * (0.875f * B1 + 0.125f * B2);
  o.w = iwy * (0.625f * T1 + 0.375f * T2) + wy * (0.625f * B1 + 0.375f * B2);
  o.x = (o.x > 0.5f) ? 1.f : 0.f;
  o.y = (o.y > 0.5f) ? 1.f : 0.f;
  o.z = (o.z > 0.5f) ? 1.f : 0.f;
  o.w = (o.w > 0.5f) ? 1.f : 0.f;
  *(float4*)&out[o4] = o;
}

extern "C" void kernel_launch(void* const* d_in, const int* in_sizes, int n_in,
                              void* d_out, int out_size, void* d_ws, size_t ws_size,
                              hipStream_t stream) {
  // setup_inputs() dict order is INTERLEAVED: cate_p0, kern_p0, cate_p1, kern_p1, ...
  const float* c0 = (const float*)d_in[0];
  const float* k0 = (const float*)d_in[1];
  const float* c1 = (const float*)d_in[2];
  const float* k1 = (const float*)d_in[3];
  const float* c2 = (const float*)d_in[4];
  const float* k2 = (const float*)d_in[5];
  const float* c3 = (const float*)d_in[6];
  const float* k3 = (const float*)d_in[7];
  const float* c4 = (const float*)d_in[8];
  const float* k4 = (const float*)d_in[9];
  const float* mf = (const float*)d_in[10];

  char* ws = (char*)d_ws;
  unsigned* hist = (unsigned*)(ws + WS_HIST);
  unsigned* meta = (unsigned*)(ws + WS_META);
  double* iou = (double*)(ws + WS_IOU);
  float* flat = (float*)(ws + WS_FLAT);
  float* cv = (float*)(ws + WS_CANDV);
  int* ci = (int*)(ws + WS_CANDI);
  double* sel_score  = (double*)(ws + WS_SEL + 0);
  unsigned* sel_grid = (unsigned*)(ws + WS_SEL + 4096);
  unsigned* sel_label= (unsigned*)(ws + WS_SEL + 8192);
  double* sel_stride = (double*)(ws + WS_SEL + 12288);
  double* upd        = (double*)(ws + WS_SEL + 16384);
  double* summask    = (double*)(ws + WS_SEL + 20480);
  double* s_score    = (double*)(ws + WS_SEL + 24576);
  unsigned* s_slot   = (unsigned*)(ws + WS_SEL + 28672);
  unsigned* s_label2 = (unsigned*)(ws + WS_SEL + 32768);
  double* s_sum      = (double*)(ws + WS_SEL + 36864);
  unsigned* up_slot  = (unsigned*)(ws + WS_SEL + 49152);
  float* kpT = (float*)(ws + WS_KPT);
  unsigned long long* mb = (unsigned long long*)(ws + WS_MB);
  double* part = (double*)(ws + WS_PART);
  unsigned short* seg = (unsigned short*)(ws + WS_SEG);
  unsigned* plist = (unsigned*)(ws + WS_PLIST);

  int maskN = out_size - 2 * MAXI;  // 100*640*960

  hipMemsetAsync(ws, 0, WS_ZEROB, stream);  // hist + meta + iou

  // NOTE: k_flat/k_compact write flat BEFORE k_sort reuses that region as plist; by the
  // time k_sort runs, flat is dead (only cv/ci are read after k_compact).
  k_flat<<<(NFLAT + 255) / 256, 256, 0, stream>>>(c0, c1, c2, c3, c4, flat, hist);
  k_pivot<<<1, 1024, 0, stream>>>(hist, meta);
  k_compact<<<(NFLAT + 255) / 256, 256, 0, stream>>>(flat, cv, ci, meta);
  k_select<<<1, 1024, 0, stream>>>(cv, ci, meta, sel_score, sel_grid, sel_label, sel_stride);
  k_gather<<<(NPREP * NKER + 255) / 256, 256, 0, stream>>>(k0, k1, k2, k3, k4, sel_grid, kpT);
  dim3 g6(MP / BP, NPREP / BN);  // 300 x 4
  k_gemm<<<g6, 256, 0, stream>>>(kpT, mf, seg, mb, part);
  k_masks<<<NPRE, 64, 0, stream>>>(mb, part, sel_score, sel_stride, summask, upd);
  k_sort<<<1, NPREP, 0, stream>>>(upd, sel_label, summask, s_score, s_slot, s_label2, s_sum, plist, meta);
  k_inter<<<64, 256, 0, stream>>>(mb, s_slot, s_sum, plist, meta, iou);
  k_nms_top<<<1, NPREP, 0, stream>>>(iou, s_score, s_label2, s_slot, (float*)d_out, maskN, up_slot);
  k_up<<<(maskN / 4 + 255) / 256, 256, 0, stream>>>(seg, up_slot, (float*)d_out, maskN);
}

// Round 7
// 600.775 us; speedup vs baseline: 5.3102x; 5.3102x over previous
//
#include <hip/hip_runtime.h>
#include <stdint.h>

#define NCLS 80
#define NKER 256
#define STOT 3872
#define NFLAT (STOT*NCLS)   // 309760
#define NPRE 500
#define NPREP 512
#define MAXI 100
#define MH 160
#define MW 240
#define MP (MH*MW)          // 38400
#define OH 640
#define OW 960
#define NWORD 600           // 38400/64
#define PARTW 300           // 38400/128

// GEMM tiling (round-5 verified shape + reg prefetch)
#define BN 64
#define BP 128
#define BK 32

// ---- workspace byte offsets ----
#define WS_HIST   0u          // 65536 u32 = 262144
#define WS_META   262144u     // counters
#define WS_CMP    266240u     // 512 u64 compS bits
#define WS_MDEC   270336u     // 512 u64 m bits
#define WS_ZEROB  274432u     // memset range [0, WS_ZEROB)
#define WS_PIOU   274432u     // 124750 f64 pair iou = 998,000 -> ends 1,272,432
#define WS_FLAT   2266240u    // 309760 f32 (dead after k_compact; reused as plist)
#define WS_CANDV  3505280u    // 4096 f32
#define WS_CANDI  3521664u    // 4096 i32
#define WS_SEL    3538048u    // 13 arrays x 4096B
#define WS_KPT    3591296u    // 256*512 f32 = 524,288
#define WS_MB     4115584u    // 500*600 u64 = 2,400,000
#define WS_PART   6515584u    // 500*300 f64 = 1,200,000
#define WS_SEG    7715584u    // 500*38400 u16 (bf16) -> ends ~46.1MB
#define WS_PLIST  WS_FLAT     // 124750 u32 = 499KB < flat region

__device__ __forceinline__ float bf2f(unsigned short u) { return __uint_as_float(((unsigned)u) << 16); }
__device__ __forceinline__ unsigned short f2bf(float f) {
  unsigned b = __float_as_uint(f);
  return (unsigned short)((b + 0x7fffu + ((b >> 16) & 1u)) >> 16);
}
// monotone float->uint key (total order matching <)
__device__ __forceinline__ unsigned fkey(float f) {
  unsigned b = __float_as_uint(f);
  return b ^ ((b & 0x80000000u) ? 0xFFFFFFFFu : 0x80000000u);
}

// ---------- K1: point-NMS + threshold in LOGIT space (exact-equivalent, no exp) ----------
__global__ __launch_bounds__(256) void k_flat(
    const float* __restrict__ c0, const float* __restrict__ c1, const float* __restrict__ c2,
    const float* __restrict__ c3, const float* __restrict__ c4,
    float* __restrict__ flat, unsigned* __restrict__ hist) {
  int idx = blockIdx.x * 256 + threadIdx.x;
  if (idx >= NFLAT) return;
  int s = idx / NCLS, c = idx - s * NCLS;
  const float* base; int g, cell;
  if (s < 1600)      { base = c0; g = 40; cell = s; }
  else if (s < 2896) { base = c1; g = 36; cell = s - 1600; }
  else if (s < 3472) { base = c2; g = 24; cell = s - 2896; }
  else if (s < 3728) { base = c3; g = 16; cell = s - 3472; }
  else               { base = c4; g = 12; cell = s - 3728; }
  int i = cell / g, j = cell - i * g;
  const float* ch = base + c * g * g;
  float x = ch[i * g + j];
  float m = x;
  if (i > 0 && j > 0) m = fmaxf(m, ch[(i - 1) * g + j - 1]);
  if (i > 0)          m = fmaxf(m, ch[(i - 1) * g + j]);
  if (j > 0)          m = fmaxf(m, ch[i * g + j - 1]);
  bool pass = (x >= m) && ((double)x > -2.1972245773362196 /* ln(1/9) */);
  flat[idx] = pass ? x : __int_as_float(0xFF800000);  // -inf sentinel
  if (pass) atomicAdd(&hist[fkey(x) >> 16], 1u);
}

// ---------- K2: pivot bucket so that count(>= pivot) >= 500 ----------
__global__ void k_pivot(const unsigned* __restrict__ hist, unsigned* __restrict__ meta) {
  __shared__ unsigned csum[1024];
  int t = threadIdx.x;
  int hi = 65536 - t * 64, lo = hi - 64;
  unsigned s = 0;
  for (int b = lo; b < hi; ++b) s += hist[b];
  csum[t] = s;
  __syncthreads();
  if (t == 0) {
    unsigned cum = 0;
    for (int cch = 0; cch < 1024; ++cch) {
      if (cum + csum[cch] >= NPRE) {
        int chi = 65536 - cch * 64;
        for (int b = chi - 1; b >= chi - 64; --b) {
          if (cum + hist[b] >= NPRE) { meta[1] = (unsigned)b; return; }
          cum += hist[b];
        }
      }
      cum += csum[cch];
    }
    meta[1] = 0u;
  }
}

// ---------- K3: compact candidates (fp32 logit, index) ----------
__global__ __launch_bounds__(256) void k_compact(
    const float* __restrict__ flat, float* __restrict__ cv, int* __restrict__ ci,
    unsigned* __restrict__ meta) {
  int idx = blockIdx.x * 256 + threadIdx.x;
  if (idx >= NFLAT) return;
  float v = flat[idx];
  if (__float_as_uint(v) == 0xFF800000u) return;
  if ((fkey(v) >> 16) >= meta[1]) {
    unsigned pos = atomicAdd(&meta[0], 1u);
    if (pos < 4096u) { cv[pos] = v; ci[pos] = idx; }
  }
}

// ---------- K4: exact (logit,idx) bitonic sort, take top-500; fp64 sigmoid for winners ----------
__global__ __launch_bounds__(1024) void k_select(
    const float* __restrict__ cv, const int* __restrict__ ci, const unsigned* __restrict__ meta,
    double* __restrict__ sel_score, unsigned* __restrict__ sel_grid,
    unsigned* __restrict__ sel_label, double* __restrict__ sel_stride) {
  __shared__ float sv[4096];
  __shared__ int si[4096];
  int t = threadIdx.x;
  int n = (meta[0] < 4096u) ? (int)meta[0] : 4096;
  for (int i = t; i < 4096; i += 1024) {
    if (i < n) { sv[i] = cv[i]; si[i] = ci[i]; }
    else       { sv[i] = __int_as_float(0xFF800000); si[i] = (1 << 30) + i; }
  }
  __syncthreads();
  for (int k = 2; k <= 4096; k <<= 1)
    for (int j = k >> 1; j > 0; j >>= 1) {
      for (int i = t; i < 4096; i += 1024) {
        int ix = i ^ j;
        if (ix > i) {
          float v1 = sv[i], v2 = sv[ix]; int i1 = si[i], i2 = si[ix];
          bool b2 = (v2 > v1) || (v2 == v1 && i2 < i1);
          bool dir = (i & k) == 0;
          if (dir == b2) { sv[i] = v2; sv[ix] = v1; si[i] = i2; si[ix] = i1; }
        }
      }
      __syncthreads();
    }
  for (int i = t; i < NPREP; i += 1024) {
    if (i < NPRE && i < n) {
      int fidx = si[i];
      unsigned gi = (unsigned)fidx / NCLS;
      sel_score[i] = 1.0 / (1.0 + exp(-(double)sv[i]));
      sel_grid[i] = gi;
      sel_label[i] = (unsigned)fidx - gi * NCLS;
      sel_stride[i] = gi < 2896u ? 8.0 : (gi < 3472u ? 16.0 : 32.0);
    } else {
      sel_score[i] = 0.0; sel_grid[i] = 0u; sel_label[i] = 0u; sel_stride[i] = 1e18;
    }
  }
}

// ---------- K5: gather kernel vectors transposed kpT[k][n] ----------
__global__ __launch_bounds__(256) void k_gather(
    const float* __restrict__ k0, const float* __restrict__ k1, const float* __restrict__ k2,
    const float* __restrict__ k3, const float* __restrict__ k4,
    const unsigned* __restrict__ sel_grid, float* __restrict__ kpT) {
  int tid = blockIdx.x * 256 + threadIdx.x;
  if (tid >= NPREP * NKER) return;
  int n = tid & (NPREP - 1);
  int k = tid >> 9;
  float v = 0.f;
  if (n < NPRE) {
    unsigned gi = sel_grid[n];
    const float* base; unsigned g, cell;
    if (gi < 1600u)      { base = k0; g = 40; cell = gi; }
    else if (gi < 2896u) { base = k1; g = 36; cell = gi - 1600u; }
    else if (gi < 3472u) { base = k2; g = 24; cell = gi - 2896u; }
    else if (gi < 3728u) { base = k3; g = 16; cell = gi - 3472u; }
    else                 { base = k4; g = 12; cell = gi - 3728u; }
    v = base[(unsigned)k * g * g + cell];
  }
  kpT[k * NPREP + n] = v;
}

// ---------- K6: fp64 GEMM (round-5 shape) + register prefetch + fused epilogue ----------
// 64n x 128p tile, BK=32, 256 threads, micro 4n x 8p, LDS 48KB -> 3 blocks/CU.
// fma chain per output: ascending k over identical f64 values -> bit-identical to round 5.
__global__ __launch_bounds__(256, 3) void k_gemm(
    const float* __restrict__ kpT, const float* __restrict__ mf,
    unsigned short* __restrict__ seg, unsigned long long* __restrict__ mb,
    double* __restrict__ part) {
  __shared__ double Asd[BK][BN];   // 16KB  [k][n]
  __shared__ double Bsd[BK][BP];   // 32KB  [k][p]
  int p0 = blockIdx.x * BP, n0 = blockIdx.y * BN;
  int tid = threadIdx.x;
  int tp = tid & 15, tn = tid >> 4;
  double acc[4][8] = {};
  float2 pa[4], pb[8];
  // prologue: tile 0 -> regs
#pragma unroll
  for (int it = 0; it < 4; ++it) {
    int q = it * 256 + tid; int row = q >> 5, c2 = q & 31;
    pa[it] = *(const float2*)&kpT[row * NPREP + n0 + c2 * 2];
  }
#pragma unroll
  for (int it = 0; it < 8; ++it) {
    int q = it * 256 + tid; int row = q >> 6, c2 = q & 63;
    pb[it] = *(const float2*)&mf[(size_t)row * MP + p0 + c2 * 2];
  }
  for (int kc = 0; kc < NKER; kc += BK) {
    // regs -> LDS (convert to f64)
#pragma unroll
    for (int it = 0; it < 4; ++it) {
      int q = it * 256 + tid; int row = q >> 5, c2 = q & 31;
      double2 d; d.x = (double)pa[it].x; d.y = (double)pa[it].y;
      *(double2*)&Asd[row][c2 * 2] = d;
    }
#pragma unroll
    for (int it = 0; it < 8; ++it) {
      int q = it * 256 + tid; int row = q >> 6, c2 = q & 63;
      double2 d; d.x = (double)pb[it].x; d.y = (double)pb[it].y;
      *(double2*)&Bsd[row][c2 * 2] = d;
    }
    __syncthreads();
    // prefetch next tile into regs while computing this one
    if (kc + BK < NKER) {
#pragma unroll
      for (int it = 0; it < 4; ++it) {
        int q = it * 256 + tid; int row = q >> 5, c2 = q & 31;
        pa[it] = *(const float2*)&kpT[(kc + BK + row) * NPREP + n0 + c2 * 2];
      }
#pragma unroll
      for (int it = 0; it < 8; ++it) {
        int q = it * 256 + tid; int row = q >> 6, c2 = q & 63;
        pb[it] = *(const float2*)&mf[(size_t)(kc + BK + row) * MP + p0 + c2 * 2];
      }
    }
#pragma unroll 4
    for (int k = 0; k < BK; ++k) {
      double2 a01 = *(double2*)&Asd[k][(tn << 2)];
      double2 a23 = *(double2*)&Asd[k][(tn << 2) + 2];
      double2 b0 = *(double2*)&Bsd[k][tp * 2];
      double2 b1 = *(double2*)&Bsd[k][32 + tp * 2];
      double2 b2 = *(double2*)&Bsd[k][64 + tp * 2];
      double2 b3 = *(double2*)&Bsd[k][96 + tp * 2];
      double a[4] = {a01.x, a01.y, a23.x, a23.y};
      double b[8] = {b0.x, b0.y, b1.x, b1.y, b2.x, b2.y, b3.x, b3.y};
#pragma unroll
      for (int r = 0; r < 4; ++r)
#pragma unroll
        for (int c = 0; c < 8; ++c)
          acc[r][c] = fma(a[r], b[c], acc[r][c]);
    }
    __syncthreads();
  }
  // epilogue: bit = (z>0) exact; seg/wsum via fp32 sigmoid, fp64 accum
  double* partL = (double*)&Asd[0][0];                        // [64][16] f64 (8KB)
  unsigned* nibL = (unsigned*)((char*)&Asd[0][0] + 8192);     // [64][16] u32 (4KB)
  for (int r = 0; r < 4; ++r) {
    int nl = (tn << 2) + r;
    int nn = n0 + nl;
    unsigned nb = 0; double wsum = 0.0;
    unsigned short u[8];
#pragma unroll
    for (int c = 0; c < 8; ++c) {
      float z = (float)acc[r][c];
      float sf = 1.0f / (1.0f + __expf(-z));
      u[c] = f2bf(sf);
      if (acc[r][c] > 0.0) { nb |= 1u << c; wsum += (double)sf; }
    }
    if (nn < NPRE) {
#pragma unroll
      for (int g = 0; g < 4; ++g) {
        ushort2 o; o.x = u[2 * g]; o.y = u[2 * g + 1];
        *(ushort2*)&seg[(size_t)nn * MP + p0 + g * 32 + tp * 2] = o;
      }
    }
    partL[nl * 16 + tp] = wsum;
    nibL[nl * 16 + tp] = nb;
  }
  __syncthreads();
  if (tid < 64) {
    int nn = n0 + tid;
    if (nn < NPRE) {
      double ssum = 0.0; unsigned long long w0 = 0ull, w1 = 0ull;
#pragma unroll
      for (int c = 0; c < 16; ++c) {
        ssum += partL[tid * 16 + c];
        unsigned long long nb = (unsigned long long)nibL[tid * 16 + c];
        w0 |= ((nb      & 3ull) << (c * 2)) | (((nb >> 2) & 3ull) << (32 + c * 2));
        w1 |= (((nb >> 4) & 3ull) << (c * 2)) | (((nb >> 6) & 3ull) << (32 + c * 2));
      }
      int bx = blockIdx.x;
      part[nn * PARTW + bx] = ssum;
      mb[nn * NWORD + bx * 2] = w0;
      mb[nn * NWORD + bx * 2 + 1] = w1;
    }
  }
}

// ---------- K7: per-instance reduce -> updated score ----------
__global__ void k_masks(const unsigned long long* __restrict__ mb, const double* __restrict__ part,
                        const double* __restrict__ sel_score, const double* __restrict__ sel_stride,
                        double* __restrict__ summask, double* __restrict__ upd) {
  int n = blockIdx.x, t = threadIdx.x;
  int cnt = 0; double ws = 0.0;
  for (int j = t; j < NWORD; j += 64) cnt += __popcll(mb[n * NWORD + j]);
  for (int j = t; j < PARTW; j += 64) ws += part[n * PARTW + j];
  for (int o = 32; o > 0; o >>= 1) { cnt += __shfl_down(cnt, o); ws += __shfl_down(ws, o); }
  if (t == 0) {
    double cf = (double)cnt;
    double ss = ws / fmax(cf, 1.0);
    double raw = sel_score[n];
    bool keep = (cf > sel_stride[n]) && (raw > 0.0);
    summask[n] = cf;
    upd[n] = keep ? raw * ss : 0.0;
  }
}

// ---------- K8: stable descending fp64 sort + same-label-alive pair list ----------
__global__ __launch_bounds__(512) void k_sort(
    const double* __restrict__ upd, const unsigned* __restrict__ sel_label, const double* __restrict__ summask,
    double* __restrict__ s_score, unsigned* __restrict__ s_slot, unsigned* __restrict__ s_label2,
    double* __restrict__ s_sum, unsigned* __restrict__ plist, unsigned* __restrict__ meta) {
  __shared__ double sv[NPREP];
  __shared__ int si[NPREP];
  __shared__ unsigned labv[NPREP];
  int t = threadIdx.x;
  sv[t] = (t < NPRE) ? upd[t] : -1.0;
  si[t] = t;
  __syncthreads();
  for (int k = 2; k <= NPREP; k <<= 1)
    for (int j = k >> 1; j > 0; j >>= 1) {
      int ix = t ^ j;
      if (ix > t) {
        double v1 = sv[t], v2 = sv[ix]; int i1 = si[t], i2 = si[ix];
        bool b2 = (v2 > v1) || (v2 == v1 && i2 < i1);
        bool dir = (t & k) == 0;
        if (dir == b2) { sv[t] = v2; sv[ix] = v1; si[t] = i2; si[ix] = i1; }
      }
      __syncthreads();
    }
  double sc = sv[t]; int slot = si[t];
  bool alive = sc > 0.0;
  unsigned lab = sel_label[slot];
  s_score[t] = alive ? sc : 0.0;
  s_slot[t] = (unsigned)slot;
  s_label2[t] = lab;
  s_sum[t] = (alive && slot < NPRE) ? summask[slot] : 0.0;
  labv[t] = alive ? lab : (0x10000u + (unsigned)t);  // unique sentinel for dead
  __syncthreads();
  // pair enumeration: thread t = row i
  if (t < NPRE) {
    unsigned li = labv[t];
    if (li < 0x10000u) {
      for (int j = t + 1; j < NPRE; ++j) {
        if (labv[j] == li) {
          unsigned pos = atomicAdd(&meta[2], 1u);
          plist[pos] = ((unsigned)t << 16) | (unsigned)j;
        }
      }
    }
  }
}

// ---------- K9: per-pair IoU via popcount + atomicMax compS[j] ----------
__global__ __launch_bounds__(256) void k_inter(
    const unsigned long long* __restrict__ mb, const unsigned* __restrict__ s_slot,
    const double* __restrict__ s_sum, const unsigned* __restrict__ plist,
    const unsigned* __restrict__ meta, double* __restrict__ piou,
    unsigned long long* __restrict__ cmp_bits) {
  int wid = (blockIdx.x * 256 + threadIdx.x) >> 6;   // 0..255
  int lane = threadIdx.x & 63;
  unsigned npair = meta[2];
  for (unsigned pp = wid; pp < npair; pp += 256) {
    unsigned pk = plist[pp];
    int i = (int)(pk >> 16), j = (int)(pk & 0xFFFFu);
    const unsigned long long* A = mb + (size_t)s_slot[i] * NWORD;
    const unsigned long long* B = mb + (size_t)s_slot[j] * NWORD;
    int c = 0;
    for (int wd = lane; wd < NWORD; wd += 64) c += __popcll(A[wd] & B[wd]);
    for (int o = 32; o > 0; o >>= 1) c += __shfl_down(c, o);
    if (lane == 0) {
      double inter = (double)c;
      double uni = s_sum[i] + s_sum[j] - inter;
      double val = (uni > 0.0) ? inter / fmax(uni, 1.0) : 0.0;
      piou[pp] = val;
      if (val > 0.0)
        atomicMax(&cmp_bits[j], (unsigned long long)__double_as_longlong(val));
    }
  }
}

// ---------- K10: decay max over pairs: m[j] = max(0, d^2 - compS[i]^2) ----------
__global__ __launch_bounds__(256) void k_decay(
    const unsigned* __restrict__ plist, const unsigned* __restrict__ meta,
    const double* __restrict__ piou, const unsigned long long* __restrict__ cmp_bits,
    unsigned long long* __restrict__ m_bits) {
  int idx = blockIdx.x * 256 + threadIdx.x;
  unsigned npair = meta[2];
  for (unsigned p = idx; p < npair; p += 2048) {
    unsigned pk = plist[p];
    int i = (int)(pk >> 16), j = (int)(pk & 0xFFFFu);
    double d = piou[p];
    double ci = __longlong_as_double((long long)cmp_bits[i]);
    double v = d * d - ci * ci;
    if (v > 0.0)
      atomicMax(&m_bits[j], (unsigned long long)__double_as_longlong(v));
  }
}

// ---------- K11: final decay + 0.05 threshold + stable top-100 ----------
__global__ __launch_bounds__(512) void k_top(
    const unsigned long long* __restrict__ m_bits, const double* __restrict__ s_score,
    const unsigned* __restrict__ s_label2, const unsigned* __restrict__ s_slot,
    float* __restrict__ d_out, int maskN, unsigned* __restrict__ up_slot) {
  __shared__ double sv[NPREP];
  __shared__ int si[NPREP];
  int t = threadIdx.x;
  double f = 0.0;
  if (t < NPRE) {
    double m = __longlong_as_double((long long)m_bits[t]);
    f = s_score[t] * exp(-2.0 * m);
    if (f < 0.05) f = 0.0;
  }
  sv[t] = f; si[t] = t;
  __syncthreads();
  for (int k = 2; k <= NPREP; k <<= 1)
    for (int j = k >> 1; j > 0; j >>= 1) {
      int ix = t ^ j;
      if (ix > t) {
        double v1 = sv[t], v2 = sv[ix]; int i1 = si[t], i2 = si[ix];
        bool b2 = (v2 > v1) || (v2 == v1 && i2 < i1);
        bool dir = (t & k) == 0;
        if (dir == b2) { sv[t] = v2; sv[ix] = v1; si[t] = i2; si[ix] = i1; }
      }
      __syncthreads();
    }
  if (t < MAXI) {
    int pos = si[t];
    d_out[maskN + t] = (float)sv[t];
    d_out[maskN + MAXI + t] = (float)s_label2[pos];
    up_slot[t] = s_slot[pos];
  }
}

// ---------- K12: 4x bilinear upsample, 4 px/thread, float4 stores ----------
__global__ __launch_bounds__(256) void k_up(const unsigned short* __restrict__ seg,
                                            const unsigned* __restrict__ up_slot,
                                            float* __restrict__ out, int maskN) {
  int o4 = (blockIdx.x * 256 + threadIdx.x) * 4;
  if (o4 >= maskN) return;
  int m = o4 / (OH * OW);
  int rem = o4 - m * (OH * OW);
  int y = rem / OW;
  int x = rem - y * OW;
  int a = x >> 2;
  const unsigned short* row = seg + (size_t)up_slot[m] * MP;
  float sy = y * 0.25f - 0.375f;
  int y0 = (int)floorf(sy);
  float wy = sy - y0;
  int y0c = max(y0, 0), y1c = min(y0 + 1, MH - 1);
  const unsigned short* r0 = row + y0c * MW;
  const unsigned short* r1 = row + y1c * MW;
  int t0 = max(a - 1, 0), t1 = a, t2 = min(a + 1, MW - 1);
  float T0 = bf2f(r0[t0]), T1 = bf2f(r0[t1]), T2 = bf2f(r0[t2]);
  float B0 = bf2f(r1[t0]), B1 = bf2f(r1[t1]), B2 = bf2f(r1[t2]);
  float iwy = 1.f - wy;
  float4 o;
  o.x = iwy * (0.375f * T0 + 0.625f * T1) + wy * (0.375f * B0 + 0.625f * B1);
  o.y = iwy * (0.125f * T0 + 0.875f * T1) + wy * (0.125f * B0 + 0.875f * B1);
  o.z = iwy * (0.875f * T1 + 0.125f * T2) + wy * (0.875f * B1 + 0.125f * B2);
  o.w = iwy * (0.625f * T1 + 0.375f * T2) + wy * (0.625f * B1 + 0.375f * B2);
  o.x = (o.x > 0.5f) ? 1.f : 0.f;
  o.y = (o.y > 0.5f) ? 1.f : 0.f;
  o.z = (o.z > 0.5f) ? 1.f : 0.f;
  o.w = (o.w > 0.5f) ? 1.f : 0.f;
  *(float4*)&out[o4] = o;
}

extern "C" void kernel_launch(void* const* d_in, const int* in_sizes, int n_in,
                              void* d_out, int out_size, void* d_ws, size_t ws_size,
                              hipStream_t stream) {
  // setup_inputs() dict order is INTERLEAVED: cate_p0, kern_p0, cate_p1, kern_p1, ...
  const float* c0 = (const float*)d_in[0];
  const float* k0 = (const float*)d_in[1];
  const float* c1 = (const float*)d_in[2];
  const float* k1 = (const float*)d_in[3];
  const float* c2 = (const float*)d_in[4];
  const float* k2 = (const float*)d_in[5];
  const float* c3 = (const float*)d_in[6];
  const float* k3 = (const float*)d_in[7];
  const float* c4 = (const float*)d_in[8];
  const float* k4 = (const float*)d_in[9];
  const float* mf = (const float*)d_in[10];

  char* ws = (char*)d_ws;
  unsigned* hist = (unsigned*)(ws + WS_HIST);
  unsigned* meta = (unsigned*)(ws + WS_META);
  unsigned long long* cmp_bits = (unsigned long long*)(ws + WS_CMP);
  unsigned long long* m_bits = (unsigned long long*)(ws + WS_MDEC);
  double* piou = (double*)(ws + WS_PIOU);
  float* flat = (float*)(ws + WS_FLAT);
  float* cv = (float*)(ws + WS_CANDV);
  int* ci = (int*)(ws + WS_CANDI);
  double* sel_score  = (double*)(ws + WS_SEL + 0);
  unsigned* sel_grid = (unsigned*)(ws + WS_SEL + 4096);
  unsigned* sel_label= (unsigned*)(ws + WS_SEL + 8192);
  double* sel_stride = (double*)(ws + WS_SEL + 12288);
  double* upd        = (double*)(ws + WS_SEL + 16384);
  double* summask    = (double*)(ws + WS_SEL + 20480);
  double* s_score    = (double*)(ws + WS_SEL + 24576);
  unsigned* s_slot   = (unsigned*)(ws + WS_SEL + 28672);
  unsigned* s_label2 = (unsigned*)(ws + WS_SEL + 32768);
  double* s_sum      = (double*)(ws + WS_SEL + 36864);
  unsigned* up_slot  = (unsigned*)(ws + WS_SEL + 49152);
  float* kpT = (float*)(ws + WS_KPT);
  unsigned long long* mb = (unsigned long long*)(ws + WS_MB);
  double* part = (double*)(ws + WS_PART);
  unsigned short* seg = (unsigned short*)(ws + WS_SEG);
  unsigned* plist = (unsigned*)(ws + WS_PLIST);

  int maskN = out_size - 2 * MAXI;  // 100*640*960

  hipMemsetAsync(ws, 0, WS_ZEROB, stream);  // hist + meta + cmp_bits + m_bits

  k_flat<<<(NFLAT + 255) / 256, 256, 0, stream>>>(c0, c1, c2, c3, c4, flat, hist);
  k_pivot<<<1, 1024, 0, stream>>>(hist, meta);
  k_compact<<<(NFLAT + 255) / 256, 256, 0, stream>>>(flat, cv, ci, meta);
  k_select<<<1, 1024, 0, stream>>>(cv, ci, meta, sel_score, sel_grid, sel_label, sel_stride);
  k_gather<<<(NPREP * NKER + 255) / 256, 256, 0, stream>>>(k0, k1, k2, k3, k4, sel_grid, kpT);
  dim3 g6(MP / BP, NPREP / BN);  // 300 x 8
  k_gemm<<<g6, 256, 0, stream>>>(kpT, mf, seg, mb, part);
  k_masks<<<NPRE, 64, 0, stream>>>(mb, part, sel_score, sel_stride, summask, upd);
  k_sort<<<1, NPREP, 0, stream>>>(upd, sel_label, summask, s_score, s_slot, s_label2, s_sum, plist, meta);
  k_inter<<<64, 256, 0, stream>>>(mb, s_slot, s_sum, plist, meta, piou, cmp_bits);
  k_decay<<<8, 256, 0, stream>>>(plist, meta, piou, cmp_bits, m_bits);
  k_top<<<1, NPREP, 0, stream>>>(m_bits, s_score, s_label2, s_slot, (float*)d_out, maskN, up_slot);
  k_up<<<(maskN / 4 + 255) / 256, 256, 0, stream>>>(seg, up_slot, (float*)d_out, maskN);
}

// Round 8
// 592.584 us; speedup vs baseline: 5.3836x; 1.0138x over previous
//
#include <hip/hip_runtime.h>
#include <stdint.h>

#define NCLS 80
#define NKER 256
#define STOT 3872
#define NFLAT (STOT*NCLS)   // 309760
#define NPRE 500
#define NPREP 512
#define MAXI 100
#define MH 160
#define MW 240
#define MP (MH*MW)          // 38400
#define OH 640
#define OW 960
#define NWORD 600           // 38400/64
#define PARTW 300           // 38400/128

// GEMM tiling: 128x128 tile, BK=16, 8x8 micro-tile, 32KB LDS
#define BN 128
#define BP 128
#define BK 16

// ---- workspace byte offsets ----
#define WS_HIST   0u          // 65536 u32 = 262144
#define WS_META   262144u     // counters
#define WS_CMP    266240u     // 512 u64 compS bits
#define WS_ZEROB  270336u     // memset range [0, WS_ZEROB)
#define WS_PIOU   274432u     // 124750 f64 pair iou
#define WS_FLAT   2266240u    // 309760 f32 (dead after k_compact; reused as plist)
#define WS_CANDV  3505280u    // 4096 f32
#define WS_CANDI  3521664u    // 4096 i32
#define WS_SEL    3538048u    // arrays x 4096B
#define WS_KPT    3591296u    // 256*512 f32 = 524,288
#define WS_MB     4115584u    // 500*600 u64 = 2,400,000
#define WS_PART   6515584u    // 500*300 f64 = 1,200,000
#define WS_SEG    7715584u    // 500*38400 u16 (bf16)
#define WS_PLIST  WS_FLAT     // 124750 u32 = 499KB < flat region

__device__ __forceinline__ float bf2f(unsigned short u) { return __uint_as_float(((unsigned)u) << 16); }
__device__ __forceinline__ unsigned short f2bf(float f) {
  unsigned b = __float_as_uint(f);
  return (unsigned short)((b + 0x7fffu + ((b >> 16) & 1u)) >> 16);
}
// monotone float->uint key (total order matching <)
__device__ __forceinline__ unsigned fkey(float f) {
  unsigned b = __float_as_uint(f);
  return b ^ ((b & 0x80000000u) ? 0xFFFFFFFFu : 0x80000000u);
}

// ---------- K1: point-NMS + threshold in LOGIT space ----------
__global__ __launch_bounds__(256) void k_flat(
    const float* __restrict__ c0, const float* __restrict__ c1, const float* __restrict__ c2,
    const float* __restrict__ c3, const float* __restrict__ c4,
    float* __restrict__ flat, unsigned* __restrict__ hist) {
  int idx = blockIdx.x * 256 + threadIdx.x;
  if (idx >= NFLAT) return;
  int s = idx / NCLS, c = idx - s * NCLS;
  const float* base; int g, cell;
  if (s < 1600)      { base = c0; g = 40; cell = s; }
  else if (s < 2896) { base = c1; g = 36; cell = s - 1600; }
  else if (s < 3472) { base = c2; g = 24; cell = s - 2896; }
  else if (s < 3728) { base = c3; g = 16; cell = s - 3472; }
  else               { base = c4; g = 12; cell = s - 3728; }
  int i = cell / g, j = cell - i * g;
  const float* ch = base + c * g * g;
  float x = ch[i * g + j];
  float m = x;
  if (i > 0 && j > 0) m = fmaxf(m, ch[(i - 1) * g + j - 1]);
  if (i > 0)          m = fmaxf(m, ch[(i - 1) * g + j]);
  if (j > 0)          m = fmaxf(m, ch[i * g + j - 1]);
  bool pass = (x >= m) && ((double)x > -2.1972245773362196 /* ln(1/9) */);
  flat[idx] = pass ? x : __int_as_float(0xFF800000);
  if (pass) atomicAdd(&hist[fkey(x) >> 16], 1u);
}

// ---------- K2: pivot bucket so that count(>= pivot) >= 500 ----------
__global__ void k_pivot(const unsigned* __restrict__ hist, unsigned* __restrict__ meta) {
  __shared__ unsigned csum[1024];
  int t = threadIdx.x;
  int hi = 65536 - t * 64, lo = hi - 64;
  unsigned s = 0;
  for (int b = lo; b < hi; ++b) s += hist[b];
  csum[t] = s;
  __syncthreads();
  if (t == 0) {
    unsigned cum = 0;
    for (int cch = 0; cch < 1024; ++cch) {
      if (cum + csum[cch] >= NPRE) {
        int chi = 65536 - cch * 64;
        for (int b = chi - 1; b >= chi - 64; --b) {
          if (cum + hist[b] >= NPRE) { meta[1] = (unsigned)b; return; }
          cum += hist[b];
        }
      }
      cum += csum[cch];
    }
    meta[1] = 0u;
  }
}

// ---------- K3: compact candidates ----------
__global__ __launch_bounds__(256) void k_compact(
    const float* __restrict__ flat, float* __restrict__ cv, int* __restrict__ ci,
    unsigned* __restrict__ meta) {
  int idx = blockIdx.x * 256 + threadIdx.x;
  if (idx >= NFLAT) return;
  float v = flat[idx];
  if (__float_as_uint(v) == 0xFF800000u) return;
  if ((fkey(v) >> 16) >= meta[1]) {
    unsigned pos = atomicAdd(&meta[0], 1u);
    if (pos < 4096u) { cv[pos] = v; ci[pos] = idx; }
  }
}

// ---------- K4: exact (logit,idx) bitonic sort, top-500; fp64 sigmoid for winners ----------
__global__ __launch_bounds__(1024) void k_select(
    const float* __restrict__ cv, const int* __restrict__ ci, const unsigned* __restrict__ meta,
    double* __restrict__ sel_score, unsigned* __restrict__ sel_grid,
    unsigned* __restrict__ sel_label, double* __restrict__ sel_stride) {
  __shared__ float sv[4096];
  __shared__ int si[4096];
  int t = threadIdx.x;
  int n = (meta[0] < 4096u) ? (int)meta[0] : 4096;
  for (int i = t; i < 4096; i += 1024) {
    if (i < n) { sv[i] = cv[i]; si[i] = ci[i]; }
    else       { sv[i] = __int_as_float(0xFF800000); si[i] = (1 << 30) + i; }
  }
  __syncthreads();
  for (int k = 2; k <= 4096; k <<= 1)
    for (int j = k >> 1; j > 0; j >>= 1) {
      for (int i = t; i < 4096; i += 1024) {
        int ix = i ^ j;
        if (ix > i) {
          float v1 = sv[i], v2 = sv[ix]; int i1 = si[i], i2 = si[ix];
          bool b2 = (v2 > v1) || (v2 == v1 && i2 < i1);
          bool dir = (i & k) == 0;
          if (dir == b2) { sv[i] = v2; sv[ix] = v1; si[i] = i2; si[ix] = i1; }
        }
      }
      __syncthreads();
    }
  for (int i = t; i < NPREP; i += 1024) {
    if (i < NPRE && i < n) {
      int fidx = si[i];
      unsigned gi = (unsigned)fidx / NCLS;
      sel_score[i] = 1.0 / (1.0 + exp(-(double)sv[i]));
      sel_grid[i] = gi;
      sel_label[i] = (unsigned)fidx - gi * NCLS;
      sel_stride[i] = gi < 2896u ? 8.0 : (gi < 3472u ? 16.0 : 32.0);
    } else {
      sel_score[i] = 0.0; sel_grid[i] = 0u; sel_label[i] = 0u; sel_stride[i] = 1e18;
    }
  }
}

// ---------- K5: gather kernel vectors transposed kpT[k][n] ----------
__global__ __launch_bounds__(256) void k_gather(
    const float* __restrict__ k0, const float* __restrict__ k1, const float* __restrict__ k2,
    const float* __restrict__ k3, const float* __restrict__ k4,
    const unsigned* __restrict__ sel_grid, float* __restrict__ kpT) {
  int tid = blockIdx.x * 256 + threadIdx.x;
  if (tid >= NPREP * NKER) return;
  int n = tid & (NPREP - 1);
  int k = tid >> 9;
  float v = 0.f;
  if (n < NPRE) {
    unsigned gi = sel_grid[n];
    const float* base; unsigned g, cell;
    if (gi < 1600u)      { base = k0; g = 40; cell = gi; }
    else if (gi < 2896u) { base = k1; g = 36; cell = gi - 1600u; }
    else if (gi < 3472u) { base = k2; g = 24; cell = gi - 2896u; }
    else if (gi < 3728u) { base = k3; g = 16; cell = gi - 3472u; }
    else                 { base = k4; g = 12; cell = gi - 3728u; }
    v = base[(unsigned)k * g * g + cell];
  }
  kpT[k * NPREP + n] = v;
}

// ---------- K6: fp64 GEMM, 128x128 tile, BK=16, 8x8 micro, reg prefetch ----------
// launch_bounds (256,2): VGPR cap 256 -> acc[8][8]=128 VGPR fits WITHOUT spill
// (round-6's regression was the (256,4) cap=128 forcing acc to scratch).
// fma chain per output: ascending k over identical f64 values -> bit-identical decisions.
__global__ __launch_bounds__(256, 2) void k_gemm(
    const float* __restrict__ kpT, const float* __restrict__ mf,
    unsigned short* __restrict__ seg, unsigned long long* __restrict__ mb,
    double* __restrict__ part) {
  __shared__ double Asd[BK][BN];   // 16KB [k][n]
  __shared__ double Bsd[BK][BP];   // 16KB [k][p]
  int p0 = blockIdx.x * BP, n0 = blockIdx.y * BN;
  int tid = threadIdx.x;
  int tp = tid & 15, tn = tid >> 4;
  double acc[8][8] = {};
  float2 ra[4], rb[4];
  // prologue: tile 0 -> regs
#pragma unroll
  for (int it = 0; it < 4; ++it) {
    int q = it * 256 + tid; int row = q >> 6, c2 = q & 63;
    ra[it] = *(const float2*)&kpT[row * NPREP + n0 + c2 * 2];
    rb[it] = *(const float2*)&mf[(size_t)row * MP + p0 + c2 * 2];
  }
  for (int kc = 0; kc < NKER; kc += BK) {
    // regs -> LDS (convert to f64)
#pragma unroll
    for (int it = 0; it < 4; ++it) {
      int q = it * 256 + tid; int row = q >> 6, c2 = q & 63;
      double2 da; da.x = (double)ra[it].x; da.y = (double)ra[it].y;
      double2 db; db.x = (double)rb[it].x; db.y = (double)rb[it].y;
      *(double2*)&Asd[row][c2 * 2] = da;
      *(double2*)&Bsd[row][c2 * 2] = db;
    }
    __syncthreads();
    // prefetch next tile while computing this one
    if (kc + BK < NKER) {
#pragma unroll
      for (int it = 0; it < 4; ++it) {
        int q = it * 256 + tid; int row = q >> 6, c2 = q & 63;
        ra[it] = *(const float2*)&kpT[(kc + BK + row) * NPREP + n0 + c2 * 2];
        rb[it] = *(const float2*)&mf[(size_t)(kc + BK + row) * MP + p0 + c2 * 2];
      }
    }
#pragma unroll 4
    for (int k = 0; k < BK; ++k) {
      double2 A0 = *(double2*)&Asd[k][tn * 8 + 0];
      double2 A1 = *(double2*)&Asd[k][tn * 8 + 2];
      double2 A2 = *(double2*)&Asd[k][tn * 8 + 4];
      double2 A3 = *(double2*)&Asd[k][tn * 8 + 6];
      double2 B0 = *(double2*)&Bsd[k][tp * 2];
      double2 B1 = *(double2*)&Bsd[k][32 + tp * 2];
      double2 B2 = *(double2*)&Bsd[k][64 + tp * 2];
      double2 B3 = *(double2*)&Bsd[k][96 + tp * 2];
      double a[8] = {A0.x, A0.y, A1.x, A1.y, A2.x, A2.y, A3.x, A3.y};
      double b[8] = {B0.x, B0.y, B1.x, B1.y, B2.x, B2.y, B3.x, B3.y};
#pragma unroll
      for (int r = 0; r < 8; ++r)
#pragma unroll
        for (int c = 0; c < 8; ++c)
          acc[r][c] = fma(a[r], b[c], acc[r][c]);
    }
    __syncthreads();
  }
  // epilogue: bit = (z>0) exact; seg/wsum via fp32 sigmoid, fp64 accum
  double* partL = (double*)&Asd[0][0];            // [128][16] f64 = 16KB (fills Asd)
  unsigned* nibL = (unsigned*)&Bsd[0][0];         // [128][16] u32 = 8KB (in Bsd)
  for (int r = 0; r < 8; ++r) {
    int nl = (tn << 3) + r;
    int nn = n0 + nl;
    unsigned nb = 0; double wsum = 0.0;
    unsigned short u[8];
#pragma unroll
    for (int c = 0; c < 8; ++c) {
      float z = (float)acc[r][c];
      float sf = 1.0f / (1.0f + __expf(-z));
      u[c] = f2bf(sf);
      if (acc[r][c] > 0.0) { nb |= 1u << c; wsum += (double)sf; }
    }
    if (nn < NPRE) {
#pragma unroll
      for (int g = 0; g < 4; ++g) {
        ushort2 o; o.x = u[2 * g]; o.y = u[2 * g + 1];
        *(ushort2*)&seg[(size_t)nn * MP + p0 + g * 32 + tp * 2] = o;
      }
    }
    partL[nl * 16 + tp] = wsum;
    nibL[nl * 16 + tp] = nb;
  }
  __syncthreads();
  if (tid < 128) {
    int nn = n0 + tid;
    if (nn < NPRE) {
      double ssum = 0.0; unsigned long long w0 = 0ull, w1 = 0ull;
#pragma unroll
      for (int c = 0; c < 16; ++c) {
        ssum += partL[tid * 16 + c];
        unsigned long long nb = (unsigned long long)nibL[tid * 16 + c];
        w0 |= ((nb      & 3ull) << (c * 2)) | (((nb >> 2) & 3ull) << (32 + c * 2));
        w1 |= (((nb >> 4) & 3ull) << (c * 2)) | (((nb >> 6) & 3ull) << (32 + c * 2));
      }
      int bx = blockIdx.x;
      part[nn * PARTW + bx] = ssum;
      mb[nn * NWORD + bx * 2] = w0;
      mb[nn * NWORD + bx * 2 + 1] = w1;
    }
  }
}

// ---------- K7: per-instance reduce -> updated score ----------
__global__ void k_masks(const unsigned long long* __restrict__ mb, const double* __restrict__ part,
                        const double* __restrict__ sel_score, const double* __restrict__ sel_stride,
                        double* __restrict__ summask, double* __restrict__ upd) {
  int n = blockIdx.x, t = threadIdx.x;
  int cnt = 0; double ws = 0.0;
  for (int j = t; j < NWORD; j += 64) cnt += __popcll(mb[n * NWORD + j]);
  for (int j = t; j < PARTW; j += 64) ws += part[n * PARTW + j];
  for (int o = 32; o > 0; o >>= 1) { cnt += __shfl_down(cnt, o); ws += __shfl_down(ws, o); }
  if (t == 0) {
    double cf = (double)cnt;
    double ss = ws / fmax(cf, 1.0);
    double raw = sel_score[n];
    bool keep = (cf > sel_stride[n]) && (raw > 0.0);
    summask[n] = cf;
    upd[n] = keep ? raw * ss : 0.0;
  }
}

// ---------- K8: stable descending fp64 sort + same-label-alive pair list ----------
__global__ __launch_bounds__(512) void k_sort(
    const double* __restrict__ upd, const unsigned* __restrict__ sel_label, const double* __restrict__ summask,
    double* __restrict__ s_score, unsigned* __restrict__ s_slot, unsigned* __restrict__ s_label2,
    double* __restrict__ s_sum, unsigned* __restrict__ plist, unsigned* __restrict__ meta) {
  __shared__ double sv[NPREP];
  __shared__ int si[NPREP];
  __shared__ unsigned labv[NPREP];
  int t = threadIdx.x;
  sv[t] = (t < NPRE) ? upd[t] : -1.0;
  si[t] = t;
  __syncthreads();
  for (int k = 2; k <= NPREP; k <<= 1)
    for (int j = k >> 1; j > 0; j >>= 1) {
      int ix = t ^ j;
      if (ix > t) {
        double v1 = sv[t], v2 = sv[ix]; int i1 = si[t], i2 = si[ix];
        bool b2 = (v2 > v1) || (v2 == v1 && i2 < i1);
        bool dir = (t & k) == 0;
        if (dir == b2) { sv[t] = v2; sv[ix] = v1; si[t] = i2; si[ix] = i1; }
      }
      __syncthreads();
    }
  double sc = sv[t]; int slot = si[t];
  bool alive = sc > 0.0;
  unsigned lab = sel_label[slot];
  s_score[t] = alive ? sc : 0.0;
  s_slot[t] = (unsigned)slot;
  s_label2[t] = lab;
  s_sum[t] = (alive && slot < NPRE) ? summask[slot] : 0.0;
  labv[t] = alive ? lab : (0x10000u + (unsigned)t);
  __syncthreads();
  if (t < NPRE) {
    unsigned li = labv[t];
    if (li < 0x10000u) {
      for (int j = t + 1; j < NPRE; ++j) {
        if (labv[j] == li) {
          unsigned pos = atomicAdd(&meta[2], 1u);
          plist[pos] = ((unsigned)t << 16) | (unsigned)j;
        }
      }
    }
  }
}

// ---------- K9: per-pair IoU via popcount + atomicMax compS[j] ----------
__global__ __launch_bounds__(256) void k_inter(
    const unsigned long long* __restrict__ mb, const unsigned* __restrict__ s_slot,
    const double* __restrict__ s_sum, const unsigned* __restrict__ plist,
    const unsigned* __restrict__ meta, double* __restrict__ piou,
    unsigned long long* __restrict__ cmp_bits) {
  int wid = (blockIdx.x * 256 + threadIdx.x) >> 6;
  int lane = threadIdx.x & 63;
  unsigned npair = meta[2];
  for (unsigned pp = wid; pp < npair; pp += 256) {
    unsigned pk = plist[pp];
    int i = (int)(pk >> 16), j = (int)(pk & 0xFFFFu);
    const unsigned long long* A = mb + (size_t)s_slot[i] * NWORD;
    const unsigned long long* B = mb + (size_t)s_slot[j] * NWORD;
    int c = 0;
    for (int wd = lane; wd < NWORD; wd += 64) c += __popcll(A[wd] & B[wd]);
    for (int o = 32; o > 0; o >>= 1) c += __shfl_down(c, o);
    if (lane == 0) {
      double inter = (double)c;
      double uni = s_sum[i] + s_sum[j] - inter;
      double val = (uni > 0.0) ? inter / fmax(uni, 1.0) : 0.0;
      piou[pp] = val;
      if (val > 0.0)
        atomicMax(&cmp_bits[j], (unsigned long long)__double_as_longlong(val));
    }
  }
}

// ---------- K10: fused decay-max + 0.05 threshold + stable top-100 ----------
__global__ __launch_bounds__(512) void k_top(
    const unsigned* __restrict__ plist, const unsigned* __restrict__ meta,
    const double* __restrict__ piou, const unsigned long long* __restrict__ cmp_bits,
    const double* __restrict__ s_score, const unsigned* __restrict__ s_label2,
    const unsigned* __restrict__ s_slot,
    float* __restrict__ d_out, int maskN, unsigned* __restrict__ up_slot) {
  __shared__ unsigned long long mS[NPREP];
  __shared__ double sv[NPREP];
  __shared__ int si[NPREP];
  int t = threadIdx.x;
  mS[t] = 0ull;
  __syncthreads();
  unsigned npair = meta[2];
  for (unsigned p = t; p < npair; p += NPREP) {
    unsigned pk = plist[p];
    int i = (int)(pk >> 16), j = (int)(pk & 0xFFFFu);
    double d = piou[p];
    double ci = __longlong_as_double((long long)cmp_bits[i]);
    double v = d * d - ci * ci;
    if (v > 0.0)
      atomicMax(&mS[j], (unsigned long long)__double_as_longlong(v));
  }
  __syncthreads();
  double f = 0.0;
  if (t < NPRE) {
    double m = __longlong_as_double((long long)mS[t]);
    f = s_score[t] * exp(-2.0 * m);
    if (f < 0.05) f = 0.0;
  }
  sv[t] = f; si[t] = t;
  __syncthreads();
  for (int k = 2; k <= NPREP; k <<= 1)
    for (int j = k >> 1; j > 0; j >>= 1) {
      int ix = t ^ j;
      if (ix > t) {
        double v1 = sv[t], v2 = sv[ix]; int i1 = si[t], i2 = si[ix];
        bool b2 = (v2 > v1) || (v2 == v1 && i2 < i1);
        bool dir = (t & k) == 0;
        if (dir == b2) { sv[t] = v2; sv[ix] = v1; si[t] = i2; si[ix] = i1; }
      }
      __syncthreads();
    }
  if (t < MAXI) {
    int pos = si[t];
    d_out[maskN + t] = (float)sv[t];
    d_out[maskN + MAXI + t] = (float)s_label2[pos];
    up_slot[t] = s_slot[pos];
  }
}

// ---------- K11: 4x bilinear upsample, 4 px/thread, float4 stores ----------
__global__ __launch_bounds__(256) void k_up(const unsigned short* __restrict__ seg,
                                            const unsigned* __restrict__ up_slot,
                                            float* __restrict__ out, int maskN) {
  int o4 = (blockIdx.x * 256 + threadIdx.x) * 4;
  if (o4 >= maskN) return;
  int m = o4 / (OH * OW);
  int rem = o4 - m * (OH * OW);
  int y = rem / OW;
  int x = rem - y * OW;
  int a = x >> 2;
  const unsigned short* row = seg + (size_t)up_slot[m] * MP;
  float sy = y * 0.25f - 0.375f;
  int y0 = (int)floorf(sy);
  float wy = sy - y0;
  int y0c = max(y0, 0), y1c = min(y0 + 1, MH - 1);
  const unsigned short* r0 = row + y0c * MW;
  const unsigned short* r1 = row + y1c * MW;
  int t0 = max(a - 1, 0), t1 = a, t2 = min(a + 1, MW - 1);
  float T0 = bf2f(r0[t0]), T1 = bf2f(r0[t1]), T2 = bf2f(r0[t2]);
  float B0 = bf2f(r1[t0]), B1 = bf2f(r1[t1]), B2 = bf2f(r1[t2]);
  float iwy = 1.f - wy;
  float4 o;
  o.x = iwy * (0.375f * T0 + 0.625f * T1) + wy * (0.375f * B0 + 0.625f * B1);
  o.y = iwy * (0.125f * T0 + 0.875f * T1) + wy * (0.125f * B0 + 0.875f * B1);
  o.z = iwy * (0.875f * T1 + 0.125f * T2) + wy * (0.875f * B1 + 0.125f * B2);
  o.w = iwy * (0.625f * T1 + 0.375f * T2) + wy * (0.625f * B1 + 0.375f * B2);
  o.x = (o.x > 0.5f) ? 1.f : 0.f;
  o.y = (o.y > 0.5f) ? 1.f : 0.f;
  o.z = (o.z > 0.5f) ? 1.f : 0.f;
  o.w = (o.w > 0.5f) ? 1.f : 0.f;
  *(float4*)&out[o4] = o;
}

extern "C" void kernel_launch(void* const* d_in, const int* in_sizes, int n_in,
                              void* d_out, int out_size, void* d_ws, size_t ws_size,
                              hipStream_t stream) {
  // setup_inputs() dict order is INTERLEAVED: cate_p0, kern_p0, cate_p1, kern_p1, ...
  const float* c0 = (const float*)d_in[0];
  const float* k0 = (const float*)d_in[1];
  const float* c1 = (const float*)d_in[2];
  const float* k1 = (const float*)d_in[3];
  const float* c2 = (const float*)d_in[4];
  const float* k2 = (const float*)d_in[5];
  const float* c3 = (const float*)d_in[6];
  const float* k3 = (const float*)d_in[7];
  const float* c4 = (const float*)d_in[8];
  const float* k4 = (const float*)d_in[9];
  const float* mf = (const float*)d_in[10];

  char* ws = (char*)d_ws;
  unsigned* hist = (unsigned*)(ws + WS_HIST);
  unsigned* meta = (unsigned*)(ws + WS_META);
  unsigned long long* cmp_bits = (unsigned long long*)(ws + WS_CMP);
  double* piou = (double*)(ws + WS_PIOU);
  float* flat = (float*)(ws + WS_FLAT);
  float* cv = (float*)(ws + WS_CANDV);
  int* ci = (int*)(ws + WS_CANDI);
  double* sel_score  = (double*)(ws + WS_SEL + 0);
  unsigned* sel_grid = (unsigned*)(ws + WS_SEL + 4096);
  unsigned* sel_label= (unsigned*)(ws + WS_SEL + 8192);
  double* sel_stride = (double*)(ws + WS_SEL + 12288);
  double* upd        = (double*)(ws + WS_SEL + 16384);
  double* summask    = (double*)(ws + WS_SEL + 20480);
  double* s_score    = (double*)(ws + WS_SEL + 24576);
  unsigned* s_slot   = (unsigned*)(ws + WS_SEL + 28672);
  unsigned* s_label2 = (unsigned*)(ws + WS_SEL + 32768);
  double* s_sum      = (double*)(ws + WS_SEL + 36864);
  unsigned* up_slot  = (unsigned*)(ws + WS_SEL + 49152);
  float* kpT = (float*)(ws + WS_KPT);
  unsigned long long* mb = (unsigned long long*)(ws + WS_MB);
  double* part = (double*)(ws + WS_PART);
  unsigned short* seg = (unsigned short*)(ws + WS_SEG);
  unsigned* plist = (unsigned*)(ws + WS_PLIST);

  int maskN = out_size - 2 * MAXI;  // 100*640*960

  hipMemsetAsync(ws, 0, WS_ZEROB, stream);  // hist + meta + cmp_bits

  k_flat<<<(NFLAT + 255) / 256, 256, 0, stream>>>(c0, c1, c2, c3, c4, flat, hist);
  k_pivot<<<1, 1024, 0, stream>>>(hist, meta);
  k_compact<<<(NFLAT + 255) / 256, 256, 0, stream>>>(flat, cv, ci, meta);
  k_select<<<1, 1024, 0, stream>>>(cv, ci, meta, sel_score, sel_grid, sel_label, sel_stride);
  k_gather<<<(NPREP * NKER + 255) / 256, 256, 0, stream>>>(k0, k1, k2, k3, k4, sel_grid, kpT);
  dim3 g6(MP / BP, NPREP / BN);  // 300 x 4
  k_gemm<<<g6, 256, 0, stream>>>(kpT, mf, seg, mb, part);
  k_masks<<<NPRE, 64, 0, stream>>>(mb, part, sel_score, sel_stride, summask, upd);
  k_sort<<<1, NPREP, 0, stream>>>(upd, sel_label, summask, s_score, s_slot, s_label2, s_sum, plist, meta);
  k_inter<<<64, 256, 0, stream>>>(mb, s_slot, s_sum, plist, meta, piou, cmp_bits);
  k_top<<<1, NPREP, 0, stream>>>(plist, meta, piou, cmp_bits, s_score, s_label2, s_slot,
                                 (float*)d_out, maskN, up_slot);
  k_up<<<(maskN / 4 + 255) / 256, 256, 0, stream>>>(seg, up_slot, (float*)d_out, maskN);
}